// Round 7
// baseline (166.149 us; speedup 1.0000x reference)
//
#include <hip/hip_runtime.h>
#include <math.h>

typedef float2 cplx;
typedef __attribute__((ext_vector_type(8))) short short8v;
typedef __attribute__((ext_vector_type(4))) short short4v;
typedef __attribute__((ext_vector_type(4))) float float4v;

#define TPB 256
#define IN_DIM 4000
#define NREPS 4

// 1/k! 0..15
#define C0f  1.0f
#define C1f  1.0f
#define C2f  0.5f
#define C3f  0.16666667f
#define C4f  0.041666668f
#define C5f  8.3333333e-3f
#define C6f  1.3888889e-3f
#define C7f  1.9841270e-4f
#define C8f  2.4801587e-5f
#define C9f  2.7557319e-6f
#define C10f 2.7557319e-7f
#define C11f 2.5052108e-8f
#define C12f 2.0876757e-9f
#define C13f 1.6059044e-10f
#define C14f 1.1470746e-11f
#define C15f 7.6471637e-13f

#define MFMA(A,B,C) __builtin_amdgcn_mfma_f32_16x16x32_bf16((A),(B),(C),0,0,0)

// ---------------------------------------------------------------------------
// LDS map (68640 B):
//   [0,32K)      S0: bf16 planes {rh,rl,ih,il} — B / V^T (Horner) / U^T (sqr);
//                later: Up fp32 stage (circuit phase of kernel 2)
//   [32K,64K)    S1: fp32 D-matrix W (load/WHT) -> A2^T planes -> U row-major
//                planes (sqr); later: Ud fp32 (circuit)
//   [64K,+32)    red[8]
//   [+32,+1K+..] psiA[64], psiB[64], part[256]  (circuit only)
// Plane layout: elem (a,b) at idxSw(a,b) (rows of 8 16B chunks, rotated).
// mfma tiling (verified r5/r6): wave wv -> 32x32 quadrant (mh=wv&1, nh=wv>>1),
// 2x2 16x16 tiles; lane: li=lane&15, q=lane>>4.
// A-frag: As[m=li][k=q*8+j]; B-frag: Bs[n=li][k] = R^T row n -> R[k][n].
// Right-evolving Horner: V_{j-1} = cI + cA A + A2*V_j (all commute); evolving
// operand on the R side so its layout (R^T row-major) = write_rowT output.
// ---------------------------------------------------------------------------

__device__ __forceinline__ int idxSw(int a, int b) {
    return (a << 6) + ((((b >> 3) + a) & 7) << 3) + (b & 7);
}
__device__ __forceinline__ short f2bf(float f) {   // RNE to bf16
    unsigned u = __float_as_uint(f);
    return (short)((u + 0x7FFF + ((u >> 16) & 1)) >> 16);
}
__device__ __forceinline__ float bf2f(short s) {
    return __uint_as_float(((unsigned)(unsigned short)s) << 16);
}
__device__ __forceinline__ short8v neg8(short8v a) {
    int4 u; __builtin_memcpy(&u, &a, 16);
    u.x ^= 0x80008000; u.y ^= 0x80008000; u.z ^= 0x80008000; u.w ^= 0x80008000;
    short8v r; __builtin_memcpy(&r, &u, 16); return r;
}

// C = L*R. Stored A-side = (sr, si): true L im = (AM==2 ? -si : si)  (AM=2:
// storage holds conj(L), e.g. A2^T = conj(A2)). BM==1: stored B-side rows give
// -R^T re (anti-Hermitian R read from R's own row-major storage).
template<int AM, int BM>
__device__ __forceinline__ void mm_mfma(const short* __restrict__ As,
                                        const short* __restrict__ Bs,
                                        int li, int q, int mh, int nh,
                                        float4v* __restrict__ accR,
                                        float4v* __restrict__ accI)
{
    #pragma unroll
    for (int ks = 0; ks < 2; ks++) {
        const int ch = ks * 4 + q;
        short8v arh[2], arl[2], cRh[2], cRl[2], cIh[2], cIl[2];
        #pragma unroll
        for (int dm = 0; dm < 2; dm++) {
            int r = ((mh * 2 + dm) << 4) + li;
            int off = (r << 6) + (((ch + r) & 7) << 3);
            arh[dm] = *(const short8v*)(As + off);
            arl[dm] = *(const short8v*)(As + 4096 + off);
            short8v aih = *(const short8v*)(As + 8192 + off);
            short8v ail = *(const short8v*)(As + 12288 + off);
            short8v nih = neg8(aih), nil_ = neg8(ail);
            cRh[dm] = (AM == 2) ? aih : nih;   // accR cross-term operand
            cRl[dm] = (AM == 2) ? ail : nil_;
            cIh[dm] = (AM == 2) ? nih : aih;   // accI A-im operand
            cIl[dm] = (AM == 2) ? nil_ : ail;
        }
        #pragma unroll
        for (int dn = 0; dn < 2; dn++) {
            int n = ((nh * 2 + dn) << 4) + li;
            int off = (n << 6) + (((ch + n) & 7) << 3);
            short8v brh = *(const short8v*)(Bs + off);
            short8v brl = *(const short8v*)(Bs + 4096 + off);
            short8v bih = *(const short8v*)(Bs + 8192 + off);
            short8v bil = *(const short8v*)(Bs + 12288 + off);
            if (BM == 1) { brh = neg8(brh); brl = neg8(brl); }
            #pragma unroll
            for (int dm = 0; dm < 2; dm++) {
                int ti = dm * 2 + dn;
                accR[ti] = MFMA(arh[dm], brh, accR[ti]);
                accR[ti] = MFMA(arh[dm], brl, accR[ti]);
                accR[ti] = MFMA(arl[dm], brh, accR[ti]);
                accR[ti] = MFMA(cRh[dm], bih, accR[ti]);
                accR[ti] = MFMA(cRh[dm], bil, accR[ti]);
                accR[ti] = MFMA(cRl[dm], bih, accR[ti]);
                accI[ti] = MFMA(arh[dm], bih, accI[ti]);
                accI[ti] = MFMA(arh[dm], bil, accI[ti]);
                accI[ti] = MFMA(arl[dm], bih, accI[ti]);
                accI[ti] = MFMA(cIh[dm], brh, accI[ti]);
                accI[ti] = MFMA(cIh[dm], brl, accI[ti]);
                accI[ti] = MFMA(cIl[dm], brh, accI[ti]);
            }
        }
    }
}

// C-layout tile -> row-major planes of S (b16 scatter; squarings only)
__device__ __forceinline__ void write_row(short* __restrict__ S, int li, int q,
                                          int mh, int nh,
                                          const float4v* cre, const float4v* cim)
{
    #pragma unroll
    for (int dm = 0; dm < 2; dm++)
    #pragma unroll
    for (int dn = 0; dn < 2; dn++) {
        int ti = dm * 2 + dn;
        int c = ((nh * 2 + dn) << 4) + li;
        #pragma unroll
        for (int reg = 0; reg < 4; reg++) {
            int r = ((mh * 2 + dm) << 4) + q * 4 + reg;
            int off = idxSw(r, c);
            float vr = cre[ti][reg], vi = cim[ti][reg];
            short rh = f2bf(vr), rl = f2bf(vr - bf2f(rh));
            short ih = f2bf(vi), il = f2bf(vi - bf2f(ih));
            S[off] = rh; S[4096 + off] = rl; S[8192 + off] = ih; S[12288 + off] = il;
        }
    }
}

// C-layout tile -> transposed row-major (C^T) in S (b64 packed)
__device__ __forceinline__ void write_rowT(short* __restrict__ S, int li, int q,
                                           int mh, int nh,
                                           const float4v* cre, const float4v* cim)
{
    #pragma unroll
    for (int dm = 0; dm < 2; dm++)
    #pragma unroll
    for (int dn = 0; dn < 2; dn++) {
        int ti = dm * 2 + dn;
        int c = ((nh * 2 + dn) << 4) + li;
        int k0 = ((mh * 2 + dm) << 4) + q * 4;
        int off = idxSw(c, k0);
        short4v rh, rl, ih, il;
        #pragma unroll
        for (int reg = 0; reg < 4; reg++) {
            float vr = cre[ti][reg], vi = cim[ti][reg];
            short h1 = f2bf(vr); rh[reg] = h1; rl[reg] = f2bf(vr - bf2f(h1));
            short h2 = f2bf(vi); ih[reg] = h2; il[reg] = f2bf(vi - bf2f(h2));
        }
        *(short4v*)(S + off) = rh;
        *(short4v*)(S + 4096 + off) = rl;
        *(short4v*)(S + 8192 + off) = ih;
        *(short4v*)(S + 12288 + off) = il;
    }
}

// gather lane's C-layout tile of the matrix in S (hi+lo reconstruct)
__device__ __forceinline__ void gather_tile(const short* __restrict__ S, int li, int q,
                                            int mh, int nh, float4v* bre, float4v* bim)
{
    #pragma unroll
    for (int dm = 0; dm < 2; dm++)
    #pragma unroll
    for (int dn = 0; dn < 2; dn++) {
        int ti = dm * 2 + dn;
        int c = ((nh * 2 + dn) << 4) + li;
        #pragma unroll
        for (int reg = 0; reg < 4; reg++) {
            int r = ((mh * 2 + dm) << 4) + q * 4 + reg;
            int off = idxSw(r, c);
            bre[ti][reg] = bf2f(S[off]) + bf2f(S[4096 + off]);
            bim[ti][reg] = bf2f(S[8192 + off]) + bf2f(S[12288 + off]);
        }
    }
}

__device__ __forceinline__ void adddiag(float4v* ure, float cI, int li, int q, int mh, int nh)
{
    #pragma unroll
    for (int dm = 0; dm < 2; dm++)
    #pragma unroll
    for (int dn = 0; dn < 2; dn++) {
        if (2 * mh + dm == 2 * nh + dn) {
            #pragma unroll
            for (int e = 0; e < 4; e++)
                if (li == q * 4 + e) ure[dm * 2 + dn][e] += cI;
        }
    }
}

__device__ __forceinline__ void pauli_masks(int p, int& xm, int& zm) {
    xm = 0; zm = 0;
    #pragma unroll
    for (int k = 0; k < 6; k++) {
        int lo = (p >> (2 * k)) & 1;
        int hi = (p >> (2 * k + 1)) & 1;
        zm |= hi << k;
        xm |= (hi ^ lo) << k;
    }
}
__device__ __forceinline__ cplx pauli_phase(float v, int xm, int zm) {
    int ny = __popc(xm & zm) & 3;
    if (ny == 0) return make_float2(v, 0.f);
    if (ny == 1) return make_float2(0.f, -v);
    if (ny == 2) return make_float2(-v, 0.f);
    return make_float2(0.f, v);
}

// Full expm: loads H coefficients from src, leaves U = exp(-iH) in C-layout
// regs (ure/uim). On return all LDS reads are fenced (safe to overwrite).
__device__ __forceinline__ void expm_core(char* __restrict__ LDS,
                                          const float* __restrict__ src, bool isW,
                                          int t, float4v* ure, float4v* uim)
{
    short* S0 = (short*)LDS;
    short* S1 = (short*)(LDS + 32768);
    cplx*  W  = (cplx*)(LDS + 32768);
    float* red = (float*)(LDS + 65536);
    const int lane = t & 63, wv = t >> 6;

    // ---- load coefficients -> W[m=xmask][z=zmask]; wave-reduced sumsq ----
    float sumsq = 0.f;
    #pragma unroll
    for (int n = 0; n < 16; n++) {
        int p = t + TPB * n;
        float v = isW ? ((p == 0) ? 0.f : src[p - 1])
                      : ((p < IN_DIM) ? src[p] : 0.f);
        sumsq += v * v;
        int xm, zm; pauli_masks(p, xm, zm);
        W[(xm << 6) + zm] = pauli_phase(v, xm, zm);
    }
    #pragma unroll
    for (int d = 32; d >= 1; d >>= 1) sumsq += __shfl_xor(sumsq, d, 64);
    if (lane == 0) red[wv] = sumsq;
    __syncthreads();

    // ---- Frobenius prescale: ||B||_2 <= fro/2^s1 in (4,8] ----
    float fro = sqrtf(64.f * (red[0] + red[1] + red[2] + red[3]));
    int s1 = 0; { float nn = fro; while (nn > 8.f && s1 < 24) { nn *= 0.5f; s1++; } }
    float sc1 = exp2f((float)(-s1));

    // ---- in-register WHT: lane = z-index, 16 rows per wave ----
    cplx hv[16];
    #pragma unroll
    for (int rr = 0; rr < 16; rr++) hv[rr] = W[(((wv << 4) + rr) << 6) + lane];
    #pragma unroll
    for (int d = 1; d < 64; d <<= 1) {
        float sg = (lane & d) ? -1.f : 1.f;
        #pragma unroll
        for (int rr = 0; rr < 16; rr++) {
            float px = __shfl_xor(hv[rr].x, d, 64);
            float py = __shfl_xor(hv[rr].y, d, 64);
            hv[rr].x = fmaf(sg, hv[rr].x, px);
            hv[rr].y = fmaf(sg, hv[rr].y, py);
        }
    }
    __syncthreads();

    // ---- scatter B[l][l^m] = -i*h_m(l)*sc1 -> S0 planes ----
    #pragma unroll
    for (int rr = 0; rr < 16; rr++) {
        int m = (wv << 4) + rr;
        int c = lane ^ m;
        float vr = hv[rr].y * sc1, vi = -hv[rr].x * sc1;
        short rh = f2bf(vr), rl = f2bf(vr - bf2f(rh));
        short ih = f2bf(vi), il = f2bf(vi - bf2f(ih));
        int off = idxSw(lane, c);
        S0[off] = rh; S0[4096 + off] = rl; S0[8192 + off] = ih; S0[12288 + off] = il;
    }
    __syncthreads();

    const int li = lane & 15, q = lane >> 4;
    const int mh = wv & 1, nh = wv >> 1;
    const float4v z4 = {0.f, 0.f, 0.f, 0.f};
    float4v accR[4], accI[4];
    #define ZERO_ACC _Pragma("unroll") for (int i2 = 0; i2 < 4; i2++) { accR[i2]=z4; accI[i2]=z4; }

    // ---- mm1: B2 = B*B (A-side S0 plain; B-side S0 anti-Herm neg-re) ----
    ZERO_ACC
    mm_mfma<0, 1>(S0, S0, li, q, mh, nh, accR, accI);
    float ss = 0.f;
    #pragma unroll
    for (int ti = 0; ti < 4; ti++)
        #pragma unroll
        for (int e = 0; e < 4; e++)
            ss += accR[ti][e]*accR[ti][e] + accI[ti][e]*accI[ti][e];
    #pragma unroll
    for (int d = 32; d >= 1; d >>= 1) ss += __shfl_xor(ss, d, 64);
    if (lane == 0) red[4 + wv] = ss;
    __syncthreads();                         // mm1 reads done; red visible

    // ---- Schatten-4 bound -> extra halvings; theta = 3.4 ----
    float bound = sqrtf(sqrtf(red[4] + red[5] + red[6] + red[7]));
    int ds = 0; { float nn = bound; while (nn > 3.4f && ds < 12) { nn *= 0.5f; ds++; } }
    const int s = s1 + ds;
    float dsc = exp2f((float)(-ds)), dsc2 = dsc * dsc;

    // ---- B tile (C-layout) for Horner combos ----
    float4v bre[4], bim[4];
    gather_tile(S0, li, q, mh, nh, bre, bim);

    // ---- S1 <- A2^T = (dsc^2*B2)^T (packed write; = conj(A2)) ----
    #pragma unroll
    for (int ti = 0; ti < 4; ti++) { ure[ti] = accR[ti] * dsc2; uim[ti] = accI[ti] * dsc2; }
    write_rowT(S1, li, q, mh, nh, ure, uim);
    __syncthreads();                         // S0 gathers done; S1 visible

    // ---- S0 <- V7^T, V7 = c14 I + c15 A ----
    {
        float ca = C15f * dsc;
        #pragma unroll
        for (int ti = 0; ti < 4; ti++) { ure[ti] = ca * bre[ti]; uim[ti] = ca * bim[ti]; }
        adddiag(ure, C14f, li, q, mh, nh);
        write_rowT(S0, li, q, mh, nh, ure, uim);
    }
    __syncthreads();

    // ---- Horner: V_j = cI_j I + cA_j A + A2*V_{j+1}, j = 6..0 ----
    const float cIc[7] = { C0f, C2f, C4f, C6f, C8f, C10f, C12f };
    const float cAc[7] = { C1f, C3f, C5f, C7f, C9f, C11f, C13f };
    for (int j = 6; j >= 0; j--) {
        ZERO_ACC
        mm_mfma<2, 0>(S1, S0, li, q, mh, nh, accR, accI);   // A2 * V_{j+1}
        __syncthreads();
        float ca = cAc[j] * dsc, cI = cIc[j];
        #pragma unroll
        for (int ti = 0; ti < 4; ti++) {
            ure[ti] = accR[ti] + ca * bre[ti];
            uim[ti] = accI[ti] + ca * bim[ti];
        }
        adddiag(ure, cI, li, q, mh, nh);
        write_rowT(S0, li, q, mh, nh, ure, uim);            // S0 <- V_j^T
        __syncthreads();
    }
    // regs = U; S0 = U^T (B-side ready for first squaring)

    // ---- s squarings: U <- U*U (A-side U in S1, B-side U^T in S0) ----
    for (int sq = 0; sq < s; sq++) {
        write_row(S1, li, q, mh, nh, ure, uim);             // S1 <- U row-major
        if (sq > 0) write_rowT(S0, li, q, mh, nh, ure, uim);
        __syncthreads();
        ZERO_ACC
        mm_mfma<0, 0>(S1, S0, li, q, mh, nh, accR, accI);
        __syncthreads();
        #pragma unroll
        for (int ti = 0; ti < 4; ti++) { ure[ti] = accR[ti]; uim[ti] = accI[ti]; }
    }
    #undef ZERO_ACC
}

// acc = M[i][:] . pin ; M plain-swizzled fp32; chunk rotation spreads banks
__device__ __forceinline__ cplx matvec_partial(const cplx* __restrict__ M,
                                               const cplx* __restrict__ pin,
                                               int i, int g)
{
    float ax = 0.f, ay = 0.f;
    const float4* Mr = (const float4*)(M + (i << 6));
    #pragma unroll
    for (int c = 0; c < 4; c++) {
        int ch = ((g << 2) + c + (i & 15)) & 15;
        int b = (ch >> 2) & 1;
        float4 m01 = Mr[(ch << 1) + b];
        float4 m23 = Mr[(ch << 1) + 1 - b];
        const cplx* p = pin + (ch << 2);
        cplx p0 = p[0], p1 = p[1], p2 = p[2], p3 = p[3];
        ax = fmaf(m01.x, p0.x, fmaf(-m01.y, p0.y, ax));
        ay = fmaf(m01.x, p0.y, fmaf( m01.y, p0.x, ay));
        ax = fmaf(m01.z, p1.x, fmaf(-m01.w, p1.y, ax));
        ay = fmaf(m01.z, p1.y, fmaf( m01.w, p1.x, ay));
        ax = fmaf(m23.x, p2.x, fmaf(-m23.y, p2.y, ax));
        ay = fmaf(m23.x, p2.y, fmaf( m23.y, p2.x, ay));
        ax = fmaf(m23.z, p3.x, fmaf(-m23.w, p3.y, ax));
        ay = fmaf(m23.z, p3.y, fmaf( m23.w, p3.x, ay));
    }
    return make_float2(ax, ay);
}

// ===== kernel 1: parameter unitaries Up[r] -> ws (fp32 plain-swizzled) =====
__global__ __launch_bounds__(TPB) void up_kernel(const float* __restrict__ w,
                                                 cplx* __restrict__ ws)
{
    __shared__ float4 LDSf4[4290];          // 68640 B
    char* LDS = (char*)LDSf4;
    const int t = threadIdx.x, r = blockIdx.x;
    float4v ure[4], uim[4];
    expm_core(LDS, w + (size_t)r * 4095, true, t, ure, uim);

    const int lane = t & 63, wv = t >> 6, li = lane & 15, q = lane >> 4;
    const int mh = wv & 1, nh = wv >> 1;
    cplx* dst = ws + ((size_t)r << 12);
    #pragma unroll
    for (int dm = 0; dm < 2; dm++)
    #pragma unroll
    for (int dn = 0; dn < 2; dn++) {
        int ti = dm * 2 + dn;
        int c = ((nh * 2 + dn) << 4) + li;
        int cs = c ^ (((c >> 4) & 1) << 1);
        #pragma unroll
        for (int reg = 0; reg < 4; reg++) {
            int rr = ((mh * 2 + dm) << 4) + q * 4 + reg;
            dst[(rr << 6) + cs] = make_float2(ure[ti][reg], uim[ti][reg]);
        }
    }
}

// ===== kernel 2: fused Ud-expm + circuit; grid = B = 512 (one round) =====
__global__ __launch_bounds__(TPB) void circuit_kernel(const float* __restrict__ x,
                                                      const cplx* __restrict__ ws,
                                                      const float* __restrict__ bias,
                                                      float* __restrict__ out)
{
    __shared__ float4 LDSf4[4290];          // 68640 B
    char* LDS = (char*)LDSf4;
    const int t = threadIdx.x, b = blockIdx.x;
    float4v ure[4], uim[4];
    expm_core(LDS, x + (size_t)b * IN_DIM, false, t, ure, uim);

    cplx* Ud   = (cplx*)(LDS + 32768);      // overwrites S1 planes (fenced)
    cplx* UpS  = (cplx*)LDS;                // overwrites S0 planes
    cplx* psiA = (cplx*)(LDS + 65568);
    cplx* psiB = (cplx*)(LDS + 66080);
    cplx* part = (cplx*)(LDS + 66592);

    const int lane = t & 63, wv = t >> 6, li = lane & 15, q = lane >> 4;
    const int mh = wv & 1, nh = wv >> 1;
    #pragma unroll
    for (int dm = 0; dm < 2; dm++)
    #pragma unroll
    for (int dn = 0; dn < 2; dn++) {
        int ti = dm * 2 + dn;
        int c = ((nh * 2 + dn) << 4) + li;
        int cs = c ^ (((c >> 4) & 1) << 1);
        #pragma unroll
        for (int reg = 0; reg < 4; reg++) {
            int rr = ((mh * 2 + dm) << 4) + q * 4 + reg;
            Ud[(rr << 6) + cs] = make_float2(ure[ti][reg], uim[ti][reg]);
        }
    }
    if (t < 64) psiA[t] = make_float2(t == 0 ? 1.f : 0.f, 0.f);
    __syncthreads();

    const int i = t & 63, g = t >> 6;
    for (int r = 0; r < NREPS; r++) {
        const float4* srcv = (const float4*)(ws + ((size_t)r << 12));
        float4* dstY = (float4*)UpS;
        #pragma unroll
        for (int n = 0; n < 8; n++) dstY[n * TPB + t] = srcv[n * TPB + t];
        __syncthreads();
        part[t] = matvec_partial(Ud, psiA, i, g);
        __syncthreads();
        if (t < 64) {
            cplx a0 = part[t], a1 = part[64 + t], a2 = part[128 + t], a3 = part[192 + t];
            psiB[t] = make_float2(a0.x + a1.x + a2.x + a3.x, a0.y + a1.y + a2.y + a3.y);
        }
        __syncthreads();
        part[t] = matvec_partial(UpS, psiB, i, g);
        __syncthreads();
        if (t < 64) {
            cplx a0 = part[t], a1 = part[64 + t], a2 = part[128 + t], a3 = part[192 + t];
            psiA[t] = make_float2(a0.x + a1.x + a2.x + a3.x, a0.y + a1.y + a2.y + a3.y);
        }
        __syncthreads();
    }
    if (t < 64) {
        cplx pv = psiA[t];
        out[(b << 6) + t] = fmaf(pv.x, pv.x, fmaf(pv.y, pv.y, bias[t]));
    }
}

extern "C" void kernel_launch(void* const* d_in, const int* in_sizes, int n_in,
                              void* d_out, int out_size, void* d_ws, size_t ws_size,
                              hipStream_t stream)
{
    const float* x    = (const float*)d_in[0];
    const float* w    = (const float*)d_in[1];
    const float* bias = (const float*)d_in[2];
    float* out = (float*)d_out;
    cplx* ws   = (cplx*)d_ws;               // 4 * 32 KB = 128 KB scratch

    int B = in_sizes[0] / IN_DIM;           // 512

    hipLaunchKernelGGL(up_kernel,      dim3(NREPS), dim3(TPB), 0, stream, w, ws);
    hipLaunchKernelGGL(circuit_kernel, dim3(B),     dim3(TPB), 0, stream, x, ws, bias, out);
}

// Round 8
// 155.099 us; speedup vs baseline: 1.0712x; 1.0712x over previous
//
#include <hip/hip_runtime.h>
#include <math.h>

typedef float2 cplx;
typedef __attribute__((ext_vector_type(8))) short short8v;
typedef __attribute__((ext_vector_type(4))) short short4v;
typedef __attribute__((ext_vector_type(4))) float float4v;

#define IN_DIM 4000
#define NREPS 4

// 1/k! 0..15
#define C0f  1.0f
#define C1f  1.0f
#define C2f  0.5f
#define C3f  0.16666667f
#define C4f  0.041666668f
#define C5f  8.3333333e-3f
#define C6f  1.3888889e-3f
#define C7f  1.9841270e-4f
#define C8f  2.4801587e-5f
#define C9f  2.7557319e-6f
#define C10f 2.7557319e-7f
#define C11f 2.5052108e-8f
#define C12f 2.0876757e-9f
#define C13f 1.6059044e-10f
#define C14f 1.1470746e-11f
#define C15f 7.6471637e-13f

#define MFMA(A,B,C) __builtin_amdgcn_mfma_f32_16x16x32_bf16((A),(B),(C),0,0,0)

// ---------------------------------------------------------------------------
// LDS: S0 bf16 planes {rh,rl,ih,il} [0,32K); S1 planes / fp32 W alias
// [32K,64K); red[2*WPB] at 64K; circuit adds psiA/psiB after.
// Plane: elem (a,b) at idxSw(a,b) (8 16B-chunks/row, rotated by row).
// Tiling template: WPB=4 -> wave owns 2x2 16x16 tiles (verified r5-r7);
// WPB=16 -> wave owns 1 tile (wide up_kernel). A-frag: As[m=li][k=q*8+j];
// B-frag: Bs[n=li][k] (= R^T rows). Right-evolving Horner:
// V_{j-1} = cI + cA A + A2*V_j; A2^T = conj(A2) (Herm), B^T = -conj(B).
// ---------------------------------------------------------------------------

__device__ __forceinline__ int idxSw(int a, int b) {
    return (a << 6) + ((((b >> 3) + a) & 7) << 3) + (b & 7);
}
__device__ __forceinline__ short f2bf(float f) {   // RNE to bf16
    unsigned u = __float_as_uint(f);
    return (short)((u + 0x7FFF + ((u >> 16) & 1)) >> 16);
}
__device__ __forceinline__ float bf2f(short s) {
    return __uint_as_float(((unsigned)(unsigned short)s) << 16);
}
__device__ __forceinline__ short8v neg8(short8v a) {
    int4 u; __builtin_memcpy(&u, &a, 16);
    u.x ^= 0x80008000; u.y ^= 0x80008000; u.z ^= 0x80008000; u.w ^= 0x80008000;
    short8v r; __builtin_memcpy(&r, &u, 16); return r;
}

// C = L*R. AM=2: storage holds conj(L). BM=1: storage rows are -R^T re
// (anti-Hermitian R read from its own row-major planes).
template<int AM, int BM, int ND>
__device__ __forceinline__ void mm_mfma(const short* __restrict__ As,
                                        const short* __restrict__ Bs,
                                        int li, int q, int mb, int nb,
                                        float4v* __restrict__ accR,
                                        float4v* __restrict__ accI)
{
    #pragma unroll
    for (int ks = 0; ks < 2; ks++) {
        const int ch = ks * 4 + q;
        short8v arh[ND], arl[ND], cRh[ND], cRl[ND], cIh[ND], cIl[ND];
        #pragma unroll
        for (int dm = 0; dm < ND; dm++) {
            int r = ((mb + dm) << 4) + li;
            int off = (r << 6) + (((ch + r) & 7) << 3);
            arh[dm] = *(const short8v*)(As + off);
            arl[dm] = *(const short8v*)(As + 4096 + off);
            short8v aih = *(const short8v*)(As + 8192 + off);
            short8v ail = *(const short8v*)(As + 12288 + off);
            short8v nih = neg8(aih), nil_ = neg8(ail);
            cRh[dm] = (AM == 2) ? aih : nih;
            cRl[dm] = (AM == 2) ? ail : nil_;
            cIh[dm] = (AM == 2) ? nih : aih;
            cIl[dm] = (AM == 2) ? nil_ : ail;
        }
        #pragma unroll
        for (int dn = 0; dn < ND; dn++) {
            int n = ((nb + dn) << 4) + li;
            int off = (n << 6) + (((ch + n) & 7) << 3);
            short8v brh = *(const short8v*)(Bs + off);
            short8v brl = *(const short8v*)(Bs + 4096 + off);
            short8v bih = *(const short8v*)(Bs + 8192 + off);
            short8v bil = *(const short8v*)(Bs + 12288 + off);
            if (BM == 1) { brh = neg8(brh); brl = neg8(brl); }
            #pragma unroll
            for (int dm = 0; dm < ND; dm++) {
                int ti = dm * ND + dn;
                accR[ti] = MFMA(arh[dm], brh, accR[ti]);
                accR[ti] = MFMA(arh[dm], brl, accR[ti]);
                accR[ti] = MFMA(arl[dm], brh, accR[ti]);
                accR[ti] = MFMA(cRh[dm], bih, accR[ti]);
                accR[ti] = MFMA(cRh[dm], bil, accR[ti]);
                accR[ti] = MFMA(cRl[dm], bih, accR[ti]);
                accI[ti] = MFMA(arh[dm], bih, accI[ti]);
                accI[ti] = MFMA(arh[dm], bil, accI[ti]);
                accI[ti] = MFMA(arl[dm], bih, accI[ti]);
                accI[ti] = MFMA(cIh[dm], brh, accI[ti]);
                accI[ti] = MFMA(cIh[dm], brl, accI[ti]);
                accI[ti] = MFMA(cIl[dm], brh, accI[ti]);
            }
        }
    }
}

template<int ND>
__device__ __forceinline__ void write_row(short* __restrict__ S, int li, int q,
                                          int mb, int nb,
                                          const float4v* cre, const float4v* cim)
{
    #pragma unroll
    for (int dm = 0; dm < ND; dm++)
    #pragma unroll
    for (int dn = 0; dn < ND; dn++) {
        int ti = dm * ND + dn;
        int c = ((nb + dn) << 4) + li;
        #pragma unroll
        for (int reg = 0; reg < 4; reg++) {
            int r = ((mb + dm) << 4) + q * 4 + reg;
            int off = idxSw(r, c);
            float vr = cre[ti][reg], vi = cim[ti][reg];
            short rh = f2bf(vr), rl = f2bf(vr - bf2f(rh));
            short ih = f2bf(vi), il = f2bf(vi - bf2f(ih));
            S[off] = rh; S[4096 + off] = rl; S[8192 + off] = ih; S[12288 + off] = il;
        }
    }
}

template<int ND>
__device__ __forceinline__ void write_rowT(short* __restrict__ S, int li, int q,
                                           int mb, int nb,
                                           const float4v* cre, const float4v* cim)
{
    #pragma unroll
    for (int dm = 0; dm < ND; dm++)
    #pragma unroll
    for (int dn = 0; dn < ND; dn++) {
        int ti = dm * ND + dn;
        int c = ((nb + dn) << 4) + li;
        int k0 = ((mb + dm) << 4) + q * 4;
        int off = idxSw(c, k0);
        short4v rh, rl, ih, il;
        #pragma unroll
        for (int reg = 0; reg < 4; reg++) {
            float vr = cre[ti][reg], vi = cim[ti][reg];
            short h1 = f2bf(vr); rh[reg] = h1; rl[reg] = f2bf(vr - bf2f(h1));
            short h2 = f2bf(vi); ih[reg] = h2; il[reg] = f2bf(vi - bf2f(h2));
        }
        *(short4v*)(S + off) = rh;
        *(short4v*)(S + 4096 + off) = rl;
        *(short4v*)(S + 8192 + off) = ih;
        *(short4v*)(S + 12288 + off) = il;
    }
}

template<int ND>
__device__ __forceinline__ void gather_tile(const short* __restrict__ S, int li, int q,
                                            int mb, int nb, float4v* bre, float4v* bim)
{
    #pragma unroll
    for (int dm = 0; dm < ND; dm++)
    #pragma unroll
    for (int dn = 0; dn < ND; dn++) {
        int ti = dm * ND + dn;
        int c = ((nb + dn) << 4) + li;
        #pragma unroll
        for (int reg = 0; reg < 4; reg++) {
            int r = ((mb + dm) << 4) + q * 4 + reg;
            int off = idxSw(r, c);
            bre[ti][reg] = bf2f(S[off]) + bf2f(S[4096 + off]);
            bim[ti][reg] = bf2f(S[8192 + off]) + bf2f(S[12288 + off]);
        }
    }
}

template<int ND>
__device__ __forceinline__ void adddiag(float4v* u, float cI, int li, int q, int mb, int nb)
{
    #pragma unroll
    for (int dm = 0; dm < ND; dm++)
    #pragma unroll
    for (int dn = 0; dn < ND; dn++) {
        if (mb + dm == nb + dn) {
            #pragma unroll
            for (int e = 0; e < 4; e++)
                if (li == q * 4 + e) u[dm * ND + dn][e] += cI;
        }
    }
}

// C-layout tiles -> plain-swizzled fp32 matrix (LDS or global)
template<int ND>
__device__ __forceinline__ void store_tiles(cplx* __restrict__ dst, int li, int q,
                                            int mb, int nb,
                                            const float4v* ure, const float4v* uim)
{
    #pragma unroll
    for (int dm = 0; dm < ND; dm++)
    #pragma unroll
    for (int dn = 0; dn < ND; dn++) {
        int ti = dm * ND + dn;
        int c = ((nb + dn) << 4) + li;
        int cs = c ^ (((c >> 4) & 1) << 1);
        #pragma unroll
        for (int reg = 0; reg < 4; reg++) {
            int r = ((mb + dm) << 4) + q * 4 + reg;
            dst[(r << 6) + cs] = make_float2(ure[ti][reg], uim[ti][reg]);
        }
    }
}

__device__ __forceinline__ cplx pauli_phase(float v, int xm, int zm) {
    int ny = __popc(xm & zm) & 3;
    if (ny == 0) return make_float2(v, 0.f);
    if (ny == 1) return make_float2(0.f, -v);
    if (ny == 2) return make_float2(-v, 0.f);
    return make_float2(0.f, v);
}

// Full expm: loads H coefficients from src, leaves U = exp(-iH) in C-layout
// regs. WPB = waves/block (4: 2x2 tiles/wave; 16: 1 tile/wave). All LDS
// reads fenced on return.
template<int WPB>
__device__ __forceinline__ void expm_core(char* __restrict__ LDS,
                                          const float* __restrict__ src, bool isW,
                                          int t, float4v* ure, float4v* uim)
{
    constexpr int ND    = (WPB == 4) ? 2 : 1;
    constexpr int NT    = ND * ND;
    constexpr int TPBv  = WPB * 64;
    constexpr int LITER = 4096 / TPBv;
    constexpr int ROWS  = 64 / WPB;
    constexpr int L4    = (WPB == 4) ? 4 : 5;     // log4(TPBv)
    short* S0 = (short*)LDS;
    short* S1 = (short*)(LDS + 32768);
    cplx*  W  = (cplx*)(LDS + 32768);
    float* red = (float*)(LDS + 65536);
    const int lane = t & 63, wv = t >> 6;
    const int li = lane & 15, q = lane >> 4;
    const int mb = (WPB == 4) ? ((wv & 1) << 1) : (wv & 3);
    const int nb = (WPB == 4) ? ((wv >> 1) << 1) : (wv >> 2);

    // ---- masks of t once (base-4 digits; p = t + TPBv*n, TPBv = 4^L4) ----
    int xmt = 0, zmt = 0;
    #pragma unroll
    for (int k = 0; k < 6; k++) {
        int lo = (t >> (2 * k)) & 1, hi = (t >> (2 * k + 1)) & 1;
        zmt |= hi << k; xmt |= (hi ^ lo) << k;
    }
    // ---- load coefficients -> W[m=xmask][z=zmask]; wave-reduced sumsq ----
    float sumsq = 0.f;
    #pragma unroll
    for (int n = 0; n < LITER; n++) {
        int p = t + TPBv * n;
        int lo0 = n & 1, hi0 = (n >> 1) & 1, lo1 = (n >> 2) & 1, hi1 = (n >> 3) & 1;
        int zmn = hi0 | (hi1 << 1), xmn = (hi0 ^ lo0) | ((hi1 ^ lo1) << 1);
        int xm = xmt | (xmn << L4), zm = zmt | (zmn << L4);
        float v = isW ? ((p == 0) ? 0.f : src[p - 1])
                      : ((p < IN_DIM) ? src[p] : 0.f);
        sumsq += v * v;
        W[(xm << 6) + zm] = pauli_phase(v, xm, zm);
    }
    #pragma unroll
    for (int d = 32; d >= 1; d >>= 1) sumsq += __shfl_xor(sumsq, d, 64);
    if (lane == 0) red[wv] = sumsq;
    __syncthreads();

    // ---- Frobenius prescale: ||B||_2 <= fro/2^s1 in (4,8] ----
    float rs = 0.f;
    #pragma unroll
    for (int i2 = 0; i2 < WPB; i2++) rs += red[i2];
    float fro = sqrtf(64.f * rs);
    int s1 = 0; { float nn = fro; while (nn > 8.f && s1 < 24) { nn *= 0.5f; s1++; } }
    float sc1 = exp2f((float)(-s1));

    // ---- in-register WHT: lane = z-index, ROWS rows per wave ----
    cplx hv[ROWS];
    #pragma unroll
    for (int rr = 0; rr < ROWS; rr++) hv[rr] = W[((wv * ROWS + rr) << 6) + lane];
    #pragma unroll
    for (int d = 1; d < 64; d <<= 1) {
        float sg = (lane & d) ? -1.f : 1.f;
        #pragma unroll
        for (int rr = 0; rr < ROWS; rr++) {
            float px = __shfl_xor(hv[rr].x, d, 64);
            float py = __shfl_xor(hv[rr].y, d, 64);
            hv[rr].x = fmaf(sg, hv[rr].x, px);
            hv[rr].y = fmaf(sg, hv[rr].y, py);
        }
    }
    // (no barrier needed: hv loads complete before scatter via data dep;
    //  S1/W is next written only after the post-mm1 barrier)

    // ---- scatter B[l][l^m] = -i*h_m(l)*sc1 -> S0 planes ----
    #pragma unroll
    for (int rr = 0; rr < ROWS; rr++) {
        int m = wv * ROWS + rr;
        int c = lane ^ m;
        float vr = hv[rr].y * sc1, vi = -hv[rr].x * sc1;
        short rh = f2bf(vr), rl = f2bf(vr - bf2f(rh));
        short ih = f2bf(vi), il = f2bf(vi - bf2f(ih));
        int off = idxSw(lane, c);
        S0[off] = rh; S0[4096 + off] = rl; S0[8192 + off] = ih; S0[12288 + off] = il;
    }
    __syncthreads();

    const float4v z4 = {0.f, 0.f, 0.f, 0.f};
    float4v accR[NT], accI[NT];
    #define ZERO_ACC _Pragma("unroll") for (int i2 = 0; i2 < NT; i2++) { accR[i2]=z4; accI[i2]=z4; }

    // ---- mm1: B2 = B*B ----
    ZERO_ACC
    mm_mfma<0, 1, ND>(S0, S0, li, q, mb, nb, accR, accI);
    float ss = 0.f;
    #pragma unroll
    for (int ti = 0; ti < NT; ti++)
        #pragma unroll
        for (int e = 0; e < 4; e++)
            ss += accR[ti][e]*accR[ti][e] + accI[ti][e]*accI[ti][e];
    #pragma unroll
    for (int d = 32; d >= 1; d >>= 1) ss += __shfl_xor(ss, d, 64);
    if (lane == 0) red[WPB + wv] = ss;
    __syncthreads();

    // ---- Schatten-4 bound -> extra halvings; theta = 3.4 ----
    rs = 0.f;
    #pragma unroll
    for (int i2 = 0; i2 < WPB; i2++) rs += red[WPB + i2];
    float bound = sqrtf(sqrtf(rs));
    int ds = 0; { float nn = bound; while (nn > 3.4f && ds < 12) { nn *= 0.5f; ds++; } }
    const int s = s1 + ds;
    float dsc = exp2f((float)(-ds)), dsc2 = dsc * dsc;

    // ---- B tile (C-layout) for Horner combos ----
    float4v bre[NT], bim[NT];
    gather_tile<ND>(S0, li, q, mb, nb, bre, bim);

    // ---- S1 <- A2^T = (dsc^2*B2)^T (= conj(A2)) ----
    #pragma unroll
    for (int ti = 0; ti < NT; ti++) { ure[ti] = accR[ti] * dsc2; uim[ti] = accI[ti] * dsc2; }
    write_rowT<ND>(S1, li, q, mb, nb, ure, uim);
    __syncthreads();

    // ---- S0 <- V7^T, V7 = c14 I + c15 A ----
    {
        float ca = C15f * dsc;
        #pragma unroll
        for (int ti = 0; ti < NT; ti++) { ure[ti] = ca * bre[ti]; uim[ti] = ca * bim[ti]; }
        adddiag<ND>(ure, C14f, li, q, mb, nb);
        write_rowT<ND>(S0, li, q, mb, nb, ure, uim);
    }
    __syncthreads();

    // ---- Horner: V_j = cI_j I + cA_j A + A2*V_{j+1}, j = 6..0 ----
    const float cIc[7] = { C0f, C2f, C4f, C6f, C8f, C10f, C12f };
    const float cAc[7] = { C1f, C3f, C5f, C7f, C9f, C11f, C13f };
    for (int j = 6; j >= 0; j--) {
        ZERO_ACC
        mm_mfma<2, 0, ND>(S1, S0, li, q, mb, nb, accR, accI);
        __syncthreads();
        float ca = cAc[j] * dsc, cI = cIc[j];
        #pragma unroll
        for (int ti = 0; ti < NT; ti++) {
            ure[ti] = accR[ti] + ca * bre[ti];
            uim[ti] = accI[ti] + ca * bim[ti];
        }
        adddiag<ND>(ure, cI, li, q, mb, nb);
        write_rowT<ND>(S0, li, q, mb, nb, ure, uim);
        __syncthreads();
    }

    // ---- s squarings: U <- U*U (A-side U in S1, B-side U^T in S0) ----
    for (int sq = 0; sq < s; sq++) {
        write_row<ND>(S1, li, q, mb, nb, ure, uim);
        if (sq > 0) write_rowT<ND>(S0, li, q, mb, nb, ure, uim);
        __syncthreads();
        ZERO_ACC
        mm_mfma<0, 0, ND>(S1, S0, li, q, mb, nb, accR, accI);
        __syncthreads();
        #pragma unroll
        for (int ti = 0; ti < NT; ti++) { ure[ti] = accR[ti]; uim[ti] = accI[ti]; }
    }
    #undef ZERO_ACC
}

// wave-owned matvec: wave wv computes rows 16wv..16wv+15, k split 4-way by
// lane>>4, in-register shuffle reduce. M plain-swizzled fp32.
__device__ __forceinline__ cplx matvec_wave(const cplx* __restrict__ M,
                                            const cplx* __restrict__ pin,
                                            int lane, int wv)
{
    const int rr = (wv << 4) + (lane & 15);
    const int kc = lane >> 4;
    float ax = 0.f, ay = 0.f;
    const float4* Mr = (const float4*)(M + (rr << 6));
    #pragma unroll
    for (int c = 0; c < 4; c++) {
        int ch = ((kc << 2) + c + rr) & 15;
        int b = (ch >> 2) & 1;
        float4 m01 = Mr[(ch << 1) + b];
        float4 m23 = Mr[(ch << 1) + 1 - b];
        const cplx* p = pin + (ch << 2);
        cplx p0 = p[0], p1 = p[1], p2 = p[2], p3 = p[3];
        ax = fmaf(m01.x, p0.x, fmaf(-m01.y, p0.y, ax));
        ay = fmaf(m01.x, p0.y, fmaf( m01.y, p0.x, ay));
        ax = fmaf(m01.z, p1.x, fmaf(-m01.w, p1.y, ax));
        ay = fmaf(m01.z, p1.y, fmaf( m01.w, p1.x, ay));
        ax = fmaf(m23.x, p2.x, fmaf(-m23.y, p2.y, ax));
        ay = fmaf(m23.x, p2.y, fmaf( m23.y, p2.x, ay));
        ax = fmaf(m23.z, p3.x, fmaf(-m23.w, p3.y, ax));
        ay = fmaf(m23.z, p3.y, fmaf( m23.w, p3.x, ay));
    }
    ax += __shfl_xor(ax, 16, 64); ay += __shfl_xor(ay, 16, 64);
    ax += __shfl_xor(ax, 32, 64); ay += __shfl_xor(ay, 32, 64);
    return make_float2(ax, ay);
}

// ===== kernel 1: Up[r] -> ws, wide (16 waves) for latency hiding =====
__global__ __launch_bounds__(1024) void up_kernel(const float* __restrict__ w,
                                                  cplx* __restrict__ ws)
{
    __shared__ float4 LDSf4[4104];          // 65664 B (planes + red[32])
    char* LDS = (char*)LDSf4;
    const int t = threadIdx.x, r = blockIdx.x;
    float4v ure[1], uim[1];
    expm_core<16>(LDS, w + (size_t)r * 4095, true, t, ure, uim);

    const int lane = t & 63, wv = t >> 6, li = lane & 15, q = lane >> 4;
    store_tiles<1>(ws + ((size_t)r << 12), li, q, wv & 3, wv >> 2, ure, uim);
}

// ===== kernel 2: fused Ud-expm + circuit; grid = B = 512 (one round) =====
__global__ __launch_bounds__(256) void circuit_kernel(const float* __restrict__ x,
                                                      const cplx* __restrict__ ws,
                                                      const float* __restrict__ bias,
                                                      float* __restrict__ out)
{
    __shared__ float4 LDSf4[4168];          // 66688 B
    char* LDS = (char*)LDSf4;
    const int t = threadIdx.x, b = blockIdx.x;
    float4v ure[4], uim[4];
    expm_core<4>(LDS, x + (size_t)b * IN_DIM, false, t, ure, uim);

    cplx* Ud   = (cplx*)(LDS + 32768);      // overwrites S1 planes (fenced)
    cplx* UpS  = (cplx*)LDS;                // overwrites S0 planes
    cplx* psiA = (cplx*)(LDS + 65664);
    cplx* psiB = (cplx*)(LDS + 66176);

    const int lane = t & 63, wv = t >> 6, li = lane & 15, q = lane >> 4;
    store_tiles<2>(Ud, li, q, (wv & 1) << 1, (wv >> 1) << 1, ure, uim);
    if (t < 64) psiA[t] = make_float2(t == 0 ? 1.f : 0.f, 0.f);
    __syncthreads();

    const int rowi = (wv << 4) + (lane & 15);
    for (int r = 0; r < NREPS; r++) {
        {   // stage Up[r] into S0 region (read after the mid barrier)
            const float4* srcv = (const float4*)(ws + ((size_t)r << 12));
            float4* dstY = (float4*)UpS;
            #pragma unroll
            for (int n = 0; n < 8; n++) dstY[n * 256 + t] = srcv[n * 256 + t];
        }
        cplx v1 = matvec_wave(Ud, psiA, lane, wv);
        if (lane < 16) psiB[rowi] = v1;
        __syncthreads();                    // fences stage + psiB
        cplx v2 = matvec_wave(UpS, psiB, lane, wv);
        if (lane < 16) psiA[rowi] = v2;
        __syncthreads();                    // fences psiA + UpS reuse
    }
    if (t < 64) {
        cplx pv = psiA[t];
        out[(b << 6) + t] = fmaf(pv.x, pv.x, fmaf(pv.y, pv.y, bias[t]));
    }
}

extern "C" void kernel_launch(void* const* d_in, const int* in_sizes, int n_in,
                              void* d_out, int out_size, void* d_ws, size_t ws_size,
                              hipStream_t stream)
{
    const float* x    = (const float*)d_in[0];
    const float* w    = (const float*)d_in[1];
    const float* bias = (const float*)d_in[2];
    float* out = (float*)d_out;
    cplx* ws   = (cplx*)d_ws;               // 4 * 32 KB = 128 KB scratch

    int B = in_sizes[0] / IN_DIM;           // 512

    hipLaunchKernelGGL(up_kernel,      dim3(NREPS), dim3(1024), 0, stream, w, ws);
    hipLaunchKernelGGL(circuit_kernel, dim3(B),     dim3(256),  0, stream, x, ws, bias, out);
}